// Round 1
// baseline (338.460 us; speedup 1.0000x reference)
//
#include <hip/hip_runtime.h>

// DySample (f32): 1x1 conv (8 ch) -> pixel_shuffle(2) -> grid offsets -> bilinear
// grid_sample. B=16, C=256, H=W=64, r=2, out (16,256,128,128) float32.
//
// R3 theory: the reference's swapped grid channels mean ix varies with output
// ROW and iy with output COLUMN. A wave covers one output row -> ix ~constant,
// iy strides ~1/lane. plane[(y<<6)|x] then has lane bank-stride 64*4 mod 32 = 0:
// all 64 lanes hit one 4-bank group => ~16-way conflict on every ds_read_b128
// (the real cost behind the ~155us k_sample). Fix: XOR-swizzle the x index by
// the row, idx = (y<<6) | (x ^ (y&7)). Fill-phase waves have constant y and
// x=lane, so writes stay conflict-free and global reads stay coalesced.

#define NB 16
#define NC 256
#define NH 64
#define NW 64
#define NHO 128
#define NWO 128
#define PLANE (NH*NW)      // 4096
#define OPLANE (NHO*NWO)   // 16384

// One block per input row (b,h). 256 thr: qid=tid>>6 picks a 64-channel
// quarter, w=tid&63 the pixel. Each thread partial-sums 64 channels; LDS
// reduce across quarters; wave 0 finalizes the 4 shuffled output coords.
__global__ __launch_bounds__(256, 4) void k_offsets(
    const float* __restrict__ x,
    const float* __restrict__ weight,
    const float* __restrict__ bias,
    float2* __restrict__ coords)
{
    __shared__ float4 wl4[NC * 2];      // wl[c*8+o] = weight[o][c], 8 KiB
    __shared__ float red[4][64][8];     // 8 KiB
    float* wl = (float*)wl4;
    const int tid = threadIdx.x;
    const int qid = tid >> 6, w = tid & 63;
    const int row = blockIdx.x;         // 1024 rows total
    const int b = row >> 6, h = row & 63;

    #pragma unroll
    for (int i = 0; i < 8; ++i) {
        int idx = tid * 8 + i;
        wl[idx] = weight[(idx & 7) * NC + (idx >> 3)];
    }
    __syncthreads();

    const float* xp = x + ((size_t)b * NC + (size_t)qid * 64) * PLANE + h * NW + w;
    float acc[8];
    #pragma unroll
    for (int o = 0; o < 8; ++o) acc[o] = 0.0f;

    #pragma unroll 8
    for (int i = 0; i < 64; ++i) {
        float xv = xp[(size_t)i * PLANE];
        float4 wA = wl4[(qid * 64 + i) * 2];
        float4 wB = wl4[(qid * 64 + i) * 2 + 1];
        acc[0] = fmaf(xv, wA.x, acc[0]);
        acc[1] = fmaf(xv, wA.y, acc[1]);
        acc[2] = fmaf(xv, wA.z, acc[2]);
        acc[3] = fmaf(xv, wA.w, acc[3]);
        acc[4] = fmaf(xv, wB.x, acc[4]);
        acc[5] = fmaf(xv, wB.y, acc[5]);
        acc[6] = fmaf(xv, wB.z, acc[6]);
        acc[7] = fmaf(xv, wB.w, acc[7]);
    }
    #pragma unroll
    for (int o = 0; o < 8; ++o) red[qid][w][o] = acc[o];
    __syncthreads();

    if (tid < 64) {
        float s[8];
        #pragma unroll
        for (int o = 0; o < 8; ++o)
            s[o] = red[0][tid][o] + red[1][tid][o] + red[2][tid][o] + red[3][tid][o]
                 + bias[o];
        // pixel_shuffle: conv ch q=ry*2+rx -> out px (2h+ry, 2w+rx); ch q adds
        // to grid[...,0] (x-coord, from row linspace gh); ch q+4 -> y-coord.
        float2* cb = coords + (size_t)b * OPLANE;
        #pragma unroll
        for (int ry = 0; ry < 2; ++ry) {
            int ho = 2 * h + ry;
            float gh = fmaf((float)ho, 2.0f / 127.0f, -1.0f);
            float4 st;
            {
                int wo = 2 * tid;
                float gw = fmaf((float)wo, 2.0f / 127.0f, -1.0f);
                int q = ry * 2;
                st.x = ((gh + s[q] + 1.0f) * 64.0f - 1.0f) * 0.5f;       // ix
                st.y = ((gw + s[q + 4] + 1.0f) * 64.0f - 1.0f) * 0.5f;   // iy
            }
            {
                int wo = 2 * tid + 1;
                float gw = fmaf((float)wo, 2.0f / 127.0f, -1.0f);
                int q = ry * 2 + 1;
                st.z = ((gh + s[q] + 1.0f) * 64.0f - 1.0f) * 0.5f;
                st.w = ((gw + s[q + 4] + 1.0f) * 64.0f - 1.0f) * 0.5f;
            }
            *reinterpret_cast<float4*>(cb + ho * NWO + 2 * tid) = st;
        }
    }
}

// Swizzled plane index: element (y,x) lives at (y<<6) | (x ^ (y&7)).
// float4 element i -> bank group (i mod 8); XOR by y&7 makes fixed-x,
// consecutive-y lane patterns cycle all 8 bank groups (conflict-free).
static __device__ __forceinline__ int pidx(int y, int x)
{
    return (y << 6) | (x ^ (y & 7));
}

// Bilinear tap blend for a 4-channel float4 plane in LDS (swizzled layout).
static __device__ __forceinline__ float4 samp4(const float4* __restrict__ plane,
                                               float ix, float iy)
{
    float fx0 = floorf(ix), fy0 = floorf(iy);
    float wx1 = ix - fx0, wy1 = iy - fy0;
    float wx0 = 1.0f - wx1, wy0 = 1.0f - wy1;
    int x0 = (int)fx0, y0 = (int)fy0;
    int x1 = x0 + 1, y1 = y0 + 1;
    bool vx0 = (unsigned)x0 < 64u, vx1 = (unsigned)x1 < 64u;
    bool vy0 = (unsigned)y0 < 64u, vy1 = (unsigned)y1 < 64u;
    float w00 = (vy0 & vx0) ? wy0 * wx0 : 0.0f;
    float w01 = (vy0 & vx1) ? wy0 * wx1 : 0.0f;
    float w10 = (vy1 & vx0) ? wy1 * wx0 : 0.0f;
    float w11 = (vy1 & vx1) ? wy1 * wx1 : 0.0f;
    int x0c = min(max(x0, 0), 63), x1c = min(max(x1, 0), 63);
    int y0c = min(max(y0, 0), 63), y1c = min(max(y1, 0), 63);
    float4 a00 = plane[pidx(y0c, x0c)];
    float4 a01 = plane[pidx(y0c, x1c)];
    float4 a10 = plane[pidx(y1c, x0c)];
    float4 a11 = plane[pidx(y1c, x1c)];
    float4 r;
    r.x = w00 * a00.x + w01 * a01.x + w10 * a10.x + w11 * a11.x;
    r.y = w00 * a00.y + w01 * a01.y + w10 * a10.y + w11 * a11.y;
    r.z = w00 * a00.z + w01 * a01.z + w10 * a10.z + w11 * a11.z;
    r.w = w00 * a00.w + w01 * a01.w + w10 * a10.w + w11 * a11.w;
    return r;
}

// One block = (b, 4-channel group); 4 planes interleaved in LDS as float4,
// x index XOR-swizzled by row (see pidx). 512 thr, 2 consecutive output px
// per thread per iter. Wave = one output row => iy strides ~1/lane; swizzle
// spreads those reads across all 32 banks.
__global__ __launch_bounds__(512, 4) void k_sample(
    const float* __restrict__ x,
    const float2* __restrict__ coords,
    float* __restrict__ out)
{
    __shared__ float4 plane[PLANE];   // 64 KiB
    const int tid = threadIdx.x;
    const int g = blockIdx.x & 63;    // channel group
    const int b = blockIdx.x >> 6;

    const float* xb = x + ((size_t)(b * NC + g * 4)) * PLANE;
    #pragma unroll
    for (int i = 0; i < 8; ++i) {
        int pos = i * 512 + tid;
        float4 v;
        v.x = xb[pos];
        v.y = xb[PLANE + pos];
        v.z = xb[2 * PLANE + pos];
        v.w = xb[3 * PLANE + pos];
        plane[pidx(pos >> 6, pos & 63)] = v;   // wave: y const, x=lane -> perm
    }
    __syncthreads();

    const float4* cb4 = (const float4*)(coords + (size_t)b * OPLANE);
    float* ob = out + ((size_t)(b * NC + g * 4)) * OPLANE;

    #pragma unroll 1
    for (int it = 0; it < 16; ++it) {
        const int base = it * 1024 + tid * 2;     // 2 consecutive output px
        float4 cd = cb4[it * 512 + tid];          // (ix0,iy0,ix1,iy1)
        float4 p0 = samp4(plane, cd.x, cd.y);
        float4 p1 = samp4(plane, cd.z, cd.w);
        *reinterpret_cast<float2*>(ob + base)              = make_float2(p0.x, p1.x);
        *reinterpret_cast<float2*>(ob + OPLANE + base)     = make_float2(p0.y, p1.y);
        *reinterpret_cast<float2*>(ob + 2 * OPLANE + base) = make_float2(p0.z, p1.z);
        *reinterpret_cast<float2*>(ob + 3 * OPLANE + base) = make_float2(p0.w, p1.w);
    }
}

extern "C" void kernel_launch(void* const* d_in, const int* in_sizes, int n_in,
                              void* d_out, int out_size, void* d_ws, size_t ws_size,
                              hipStream_t stream)
{
    const float* x      = (const float*)d_in[0];
    const float* weight = (const float*)d_in[1];
    const float* bias   = (const float*)d_in[2];
    float* out = (float*)d_out;
    float2* coords = (float2*)d_ws;   // 16*16384*8 B = 2 MiB

    hipLaunchKernelGGL(k_offsets, dim3(NB * NH), dim3(256), 0, stream,
                       x, weight, bias, coords);
    hipLaunchKernelGGL(k_sample, dim3(NB * 64), dim3(512), 0, stream,
                       x, coords, out);
}